// Round 24
// baseline (262.883 us; speedup 1.0000x reference)
//
#include <hip/hip_runtime.h>
#include <hip/hip_bf16.h>
#include <cstddef>

// Problem constants (B,H,W,C)=(4,96,96,256), G=4, K=3
#define B_   4
#define H_   96
#define W_   96
#define C_   256
#define G_   4
#define CG   64      // C/G
#define NPOS 9       // K*K
#define KC   576     // K*K*CG
#define HW   (H_*W_)      // 9216
#define NPIX (B_*H_*W_)   // 36864

// 2-D pixel tile (4x16, window 6x18)
#define TM 4
#define TN 16
#define WROWS 6
#define WCOLS 18
#define WPOS  108

typedef float f32x4 __attribute__((ext_vector_type(4)));
typedef float f32x2 __attribute__((ext_vector_type(2)));
typedef short bf16x8 __attribute__((ext_vector_type(8)));

static __device__ __forceinline__ ushort f2bf(float f) {
    unsigned u = __float_as_uint(f);
    unsigned r = (u + 0x7fffu + ((u >> 16) & 1u)) >> 16;   // RNE
    return (ushort)r;
}
static __device__ __forceinline__ float bf2f(ushort u) {
    return __uint_as_float(((unsigned)u) << 16);
}
static __device__ __forceinline__ f32x2 up2(unsigned u) {
    f32x2 f;
    f.x = __uint_as_float(u << 16);
    f.y = __uint_as_float(u & 0xFFFF0000u);
    return f;
}

// ---------------------------------------------------------------------------
// K0z: zero the 128B OOB source buffer (re-zeroed every launch).
// ---------------------------------------------------------------------------
__global__ void k_zero(ushort* __restrict__ z) {
    z[threadIdx.x] = 0;
}

// ---------------------------------------------------------------------------
// Kc1: w_off [g][3][3][64][18] -> wtT split bf16 [g][oc pad 32][576]
// ---------------------------------------------------------------------------
__global__ void k_cvt_woffT(const float* __restrict__ w_off,
                            ushort* __restrict__ wtTh,
                            ushort* __restrict__ wtTl) {
    int idx = blockIdx.x * 256 + threadIdx.x;
    if (idx >= G_ * 32 * KC) return;
    int k  = idx % KC;
    int oc = (idx / KC) & 31;
    int g  = idx / (32 * KC);
    int p = k >> 6, c = k & 63;
    float v = 0.f;
    if (oc < 18) v = w_off[((size_t)(g * NPOS + p) * CG + c) * 18 + oc];
    ushort h = f2bf(v);
    wtTh[idx] = h;
    wtTl[idx] = f2bf(v - bf2f(h));
}

// ---------------------------------------------------------------------------
// Kc2: w_init [k=256][co=256] -> wT split bf16 [co][k]
// ---------------------------------------------------------------------------
__global__ void k_cvt_wT_split(const float* __restrict__ w_init,
                               ushort* __restrict__ wTh,
                               ushort* __restrict__ wTl) {
    int idx = blockIdx.x * 256 + threadIdx.x;
    if (idx >= 256 * 256) return;
    int co = idx & 255, k = idx >> 8;
    float v = w_init[(size_t)k * 256 + co];
    ushort h = f2bf(v);
    wTh[(size_t)co * 256 + k] = h;
    wTl[(size_t)co * 256 + k] = f2bf(v - bf2f(h));
}

// ---------------------------------------------------------------------------
// Kc3: w_pw [g][k=576][f=64] -> wpwT bf16 (hi only) [g][f][k=576]
// ---------------------------------------------------------------------------
__global__ void k_cvt_wpwT(const float* __restrict__ w_pw,
                           ushort* __restrict__ wpwTh) {
    int idx = blockIdx.x * 256 + threadIdx.x;
    if (idx >= G_ * KC * CG) return;
    int f = idx & 63;
    int k = (idx >> 6) % KC;
    int g = idx / (KC * CG);
    wpwTh[((size_t)g * CG + f) * KC + k] = f2bf(w_pw[((size_t)g * KC + k) * CG + f]);
}

// ---------------------------------------------------------------------------
// K1: init 1x1 conv via split-bf16 MFMA (~f32 exact). y -> (yh, yl).
// ---------------------------------------------------------------------------
__global__ void __launch_bounds__(256) k_gemm_init_mfma(
        const float* __restrict__ x,
        const ushort* __restrict__ wTh, const ushort* __restrict__ wTl,
        const float* __restrict__ bias,
        ushort* __restrict__ yh, ushort* __restrict__ yl) {
    __shared__ __align__(16) ushort ath[64][72], atl[64][72];
    __shared__ __align__(16) ushort bth[64][72], btl[64][72];
    int t = threadIdx.x;
    int px0 = blockIdx.x * 64, n0 = blockIdx.y * 64;
    int r = t >> 2, seg = (t & 3) * 16;
    int lane = t & 63, wv = t >> 6;
    int hl = lane & 15, qv = lane >> 4;
    f32x4 acc[4] = {};
    for (int kk = 0; kk < C_; kk += 64) {
        {
            const float4* xs = (const float4*)(x + (size_t)(px0 + r) * C_ + kk + seg);
            ushort hbuf[16], lbuf[16];
            #pragma unroll
            for (int j = 0; j < 4; j++) {
                float4 v = xs[j];
                float vv[4] = {v.x, v.y, v.z, v.w};
                #pragma unroll
                for (int e2 = 0; e2 < 4; e2++) {
                    ushort h = f2bf(vv[e2]);
                    hbuf[j * 4 + e2] = h;
                    lbuf[j * 4 + e2] = f2bf(vv[e2] - bf2f(h));
                }
            }
            *(uint4*)&ath[r][seg]     = *(uint4*)&hbuf[0];
            *(uint4*)&ath[r][seg + 8] = *(uint4*)&hbuf[8];
            *(uint4*)&atl[r][seg]     = *(uint4*)&lbuf[0];
            *(uint4*)&atl[r][seg + 8] = *(uint4*)&lbuf[8];
        }
        {
            size_t woff = (size_t)(n0 + r) * C_ + kk + seg;
            const uint4* qh = (const uint4*)(wTh + woff);
            const uint4* ql = (const uint4*)(wTl + woff);
            uint4 c0 = qh[0], c1 = qh[1], d0 = ql[0], d1 = ql[1];
            *(uint4*)&bth[r][seg] = c0; *(uint4*)&bth[r][seg + 8] = c1;
            *(uint4*)&btl[r][seg] = d0; *(uint4*)&btl[r][seg + 8] = d1;
        }
        __syncthreads();
        #pragma unroll
        for (int ks = 0; ks < 2; ks++) {
            bf16x8 ah_ = *(const bf16x8*)&ath[wv * 16 + hl][ks * 32 + qv * 8];
            bf16x8 al_ = *(const bf16x8*)&atl[wv * 16 + hl][ks * 32 + qv * 8];
            #pragma unroll
            for (int cg = 0; cg < 4; cg++) {
                bf16x8 bh_ = *(const bf16x8*)&bth[cg * 16 + hl][ks * 32 + qv * 8];
                bf16x8 bl_ = *(const bf16x8*)&btl[cg * 16 + hl][ks * 32 + qv * 8];
                acc[cg] = __builtin_amdgcn_mfma_f32_16x16x32_bf16(ah_, bh_, acc[cg], 0, 0, 0);
                acc[cg] = __builtin_amdgcn_mfma_f32_16x16x32_bf16(ah_, bl_, acc[cg], 0, 0, 0);
                acc[cg] = __builtin_amdgcn_mfma_f32_16x16x32_bf16(al_, bh_, acc[cg], 0, 0, 0);
            }
        }
        __syncthreads();
    }
    #pragma unroll
    for (int cg = 0; cg < 4; cg++) {
        int col = n0 + cg * 16 + hl;
        float bb = bias[col];
        #pragma unroll
        for (int rg = 0; rg < 4; rg++) {
            int row = px0 + wv * 16 + qv * 4 + rg;
            float v = acc[cg][rg] + bb;
            ushort h = f2bf(v);
            yh[(size_t)row * C_ + col] = h;
            yl[(size_t)row * C_ + col] = f2bf(v - bf2f(h));
        }
    }
}

// ---------------------------------------------------------------------------
// K2: offsets 3x3 conv (64 -> 18) via 4-term split-bf16 MFMA (f32-equiv).
// R21 version EXACTLY (85 us measured; R23's 3-term+swizzle regressed to 93).
// ---------------------------------------------------------------------------
__global__ void __launch_bounds__(256) k_offconv_mfma(
        const ushort* __restrict__ yh, const ushort* __restrict__ yl,
        const ushort* __restrict__ wtTh, const ushort* __restrict__ wtTl,
        const float* __restrict__ b_off, float* __restrict__ off_all) {
    __shared__ __align__(16) ushort swh[WPOS][72], swl[WPOS][72];  // 31.1 KB
    int g = blockIdx.y;
    int tile = blockIdx.x;
    int b = tile / 144; int trem = tile - b * 144;
    int r0 = (trem / 6) * TM;
    int c0 = (trem - (trem / 6) * 6) * TN;
    int t = threadIdx.x;
    int lane = t & 63, wv = t >> 6;
    int hl = lane & 15, qv = lane >> 4;
    const int bHW = b * HW;
    for (int i = t; i < WPOS * 32; i += 256) {
        int w = i >> 5, cq = i & 31;
        int wr = w / WCOLS, wc = w - wr * WCOLS;
        int ny = r0 - 1 + wr, nx = c0 - 1 + wc;
        unsigned vh = 0u, vl = 0u;
        if (((unsigned)ny < (unsigned)H_) && ((unsigned)nx < (unsigned)W_)) {
            size_t base = ((size_t)(bHW + ny * W_ + nx) * C_ + g * CG) >> 1;
            vh = ((const unsigned*)yh)[base + cq];
            vl = ((const unsigned*)yl)[base + cq];
        }
        *(unsigned*)&swh[w][cq * 2] = vh;
        *(unsigned*)&swl[w][cq * 2] = vl;
    }
    __syncthreads();
    f32x4 acc[2] = {};
    const ushort* Wh = wtTh + (size_t)g * 32 * KC;
    const ushort* Wl = wtTl + (size_t)g * 32 * KC;
    const size_t wbase0 = (size_t)hl * KC + qv * 8;
    bf16x8 nbh[2][2], nbl[2][2];
    #pragma unroll
    for (int ks = 0; ks < 2; ks++)
        #pragma unroll
        for (int cg = 0; cg < 2; cg++) {
            size_t wo = wbase0 + (size_t)cg * 16 * KC + ks * 32;
            nbh[ks][cg] = *(const bf16x8*)&Wh[wo];
            nbl[ks][cg] = *(const bf16x8*)&Wl[wo];
        }
    for (int p = 0; p < NPOS; p++) {
        bf16x8 cbh[2][2], cbl[2][2];
        #pragma unroll
        for (int ks = 0; ks < 2; ks++)
            #pragma unroll
            for (int cg = 0; cg < 2; cg++) {
                cbh[ks][cg] = nbh[ks][cg];
                cbl[ks][cg] = nbl[ks][cg];
            }
        if (p + 1 < NPOS) {
            #pragma unroll
            for (int ks = 0; ks < 2; ks++)
                #pragma unroll
                for (int cg = 0; cg < 2; cg++) {
                    size_t wo = wbase0 + (size_t)cg * 16 * KC + (p + 1) * 64 + ks * 32;
                    nbh[ks][cg] = *(const bf16x8*)&Wh[wo];
                    nbl[ks][cg] = *(const bf16x8*)&Wl[wo];
                }
        }
        int di = p / 3, dj = p - di * 3;
        int wbase = (wv + di) * WCOLS + dj + hl;
        #pragma unroll
        for (int ks = 0; ks < 2; ks++) {
            bf16x8 ah = *(const bf16x8*)&swh[wbase][ks * 32 + qv * 8];
            bf16x8 al = *(const bf16x8*)&swl[wbase][ks * 32 + qv * 8];
            #pragma unroll
            for (int cg = 0; cg < 2; cg++) {
                acc[cg] = __builtin_amdgcn_mfma_f32_16x16x32_bf16(ah, cbh[ks][cg], acc[cg], 0, 0, 0);
                acc[cg] = __builtin_amdgcn_mfma_f32_16x16x32_bf16(ah, cbl[ks][cg], acc[cg], 0, 0, 0);
                acc[cg] = __builtin_amdgcn_mfma_f32_16x16x32_bf16(al, cbh[ks][cg], acc[cg], 0, 0, 0);
                acc[cg] = __builtin_amdgcn_mfma_f32_16x16x32_bf16(al, cbl[ks][cg], acc[cg], 0, 0, 0);
            }
        }
    }
    #pragma unroll
    for (int cg = 0; cg < 2; cg++) {
        int oc = cg * 16 + hl;
        if (oc < 18) {
            float bo = b_off[g * 18 + oc];
            #pragma unroll
            for (int rg = 0; rg < 4; rg++) {
                int pc = qv * 4 + rg;
                int px = bHW + (r0 + wv) * W_ + (c0 + pc);
                off_all[((size_t)g * NPIX + px) * 18 + oc] = acc[cg][rg] + bo;
            }
        }
    }
}

// ---------------------------------------------------------------------------
// K3: sampling (per pass). 8 ch per lane (uint4), 8 samples per
// wave-iteration. NEW: XCD-bijective block swizzle (5184 = 8*648) --
// consecutive pixel ranges land on one XCD's L2, so overlapping bilinear
// gather footprints of neighboring pixels become L2 hits (R14 mechanism).
// ---------------------------------------------------------------------------
__global__ void __launch_bounds__(256) k_sample(
        const ushort* __restrict__ yh, const float* __restrict__ off_all,
        ushort* __restrict__ smp, int g0) {
    int gi = blockIdx.y;
    int g = g0 + gi;
    int t = threadIdx.x;
    int lane = t & 63, wv = t >> 6;
    int so = lane >> 3;          // sample-octet select 0..7
    int cq = lane & 7;           // uint4 channel index (8 ch)
    int bx = blockIdx.x;
    int sb = (bx & 7) * 648 + (bx >> 3);    // bijective (5184 = 8*648)
    int base_s = (sb * 4 + wv) * 16;
    const float* offg = off_all + (size_t)g * NPIX * 18;
    const uint4* ybu = (const uint4*)yh;        // pix stride = 32 uint4
    uint4* smp4 = (uint4*)smp + (size_t)gi * NPOS * NPIX * 8;
    #pragma unroll
    for (int q = 0; q < 2; q++) {
        int s = base_s + q * 8 + so;
        int p = s / NPIX;
        int px = s - p * NPIX;
        int di = p / 3, dj = p - di * 3;
        int b = px / HW; int r2 = px - b * HW;
        int yy = r2 / W_; int xx = r2 - yy * W_;
        float2 o2 = *(const float2*)&offg[(size_t)px * 18 + 2 * p];
        float lx = (float)(xx + dj - 1) + o2.x;
        float ly = (float)(yy + di - 1) + o2.y;
        lx = fminf(fmaxf(lx, 0.f), (float)(W_ - 1));
        ly = fminf(fmaxf(ly, 0.f), (float)(H_ - 1));
        float x0f = floorf(lx), y0f = floorf(ly);
        float x1f = fminf(x0f + 1.f, (float)(W_ - 1));
        float y1f = fminf(y0f + 1.f, (float)(H_ - 1));
        float wa = (x1f - lx) * (y1f - ly);
        float wb = (x1f - lx) * (ly - y0f);
        float wc = (lx - x0f) * (y1f - ly);
        float wd = (lx - x0f) * (ly - y0f);
        int ix0 = (int)x0f, iy0 = (int)y0f, ix1 = (int)x1f, iy1 = (int)y1f;
        int pb = (b * HW) * 32 + g * 8 + cq;
        uint4 A  = ybu[pb + (iy0 * W_ + ix0) * 32];
        uint4 Bv = ybu[pb + (iy1 * W_ + ix0) * 32];
        uint4 Cv = ybu[pb + (iy0 * W_ + ix1) * 32];
        uint4 Dv = ybu[pb + (iy1 * W_ + ix1) * 32];
        f32x2 v0 = wa * up2(A.x) + wb * up2(Bv.x) + wc * up2(Cv.x) + wd * up2(Dv.x);
        f32x2 v1 = wa * up2(A.y) + wb * up2(Bv.y) + wc * up2(Cv.y) + wd * up2(Dv.y);
        f32x2 v2 = wa * up2(A.z) + wb * up2(Bv.z) + wc * up2(Cv.z) + wd * up2(Dv.z);
        f32x2 v3 = wa * up2(A.w) + wb * up2(Bv.w) + wc * up2(Cv.w) + wd * up2(Dv.w);
        uint4 o;
        o.x = (unsigned)f2bf(v0.x) | ((unsigned)f2bf(v0.y) << 16);
        o.y = (unsigned)f2bf(v1.x) | ((unsigned)f2bf(v1.y) << 16);
        o.z = (unsigned)f2bf(v2.x) | ((unsigned)f2bf(v2.y) << 16);
        o.w = (unsigned)f2bf(v3.x) | ((unsigned)f2bf(v3.y) << 16);
        smp4[(size_t)s * 8 + cq] = o;
    }
}

// ---------------------------------------------------------------------------
// K4: window-stage + depthwise-3x3 + bf16-MFMA pointwise (per pass).
// R21 version EXACTLY (best measured: single-buffer, 3 barriers, DMA
// staging, 32 KB LDS, XCD swizzle).
// ---------------------------------------------------------------------------
__global__ void __launch_bounds__(256, 4) k_dwpw(
        const ushort* __restrict__ smp, const ushort* __restrict__ zbuf,
        const float* __restrict__ w_dw, const float* __restrict__ b_dw,
        const ushort* __restrict__ wpwTh, const float* __restrict__ b_pw,
        float* __restrict__ out, int g0) {
    __shared__ __align__(16) ushort swin[WPOS][64];   // 13.5 KB [pos][ch]
    __shared__ __align__(16) ushort ht [64][72];      //  9.0 KB
    __shared__ __align__(16) ushort wt_[64][72];      //  9.0 KB
    int gi = blockIdx.y;
    int g = g0 + gi;
    int bx = blockIdx.x;
    int tile = (bx & 7) * 72 + (bx >> 3);   // bijective (576 = 8*72)
    int b = tile / 144; int trem = tile - b * 144;
    int r0 = (trem / 6) * TM;
    int c0 = (trem - (trem / 6) * 6) * TN;
    int t = threadIdx.x;
    int lane = t & 63, wv = t >> 6;
    int hl = lane & 15, qv = lane >> 4;
    int rr = t >> 2, seg = (t & 3) * 16;
    const float* wdwg = w_dw + (size_t)g * NPOS * KC;
    const float* bdwg = b_dw + (size_t)g * KC;
    const ushort* wpwg = wpwTh + (size_t)g * CG * KC;
    const float* bpwg = b_pw + (size_t)g * CG;
    const int bHW = b * HW;
    int cp  = t & 31;          // channel pair (2cp, 2cp+1)
    int pxg = t >> 5;          // 0..7
    int pr  = pxg >> 1;        // tile row 0..3
    int ph  = pxg & 1;         // col half (8 cols each)

    // staging descriptors: 108 pos x 8 uint4 = 864 items, up to 4 per thread
    int doff[4];
    #pragma unroll
    for (int k = 0; k < 4; k++) {
        int i = t + k * 256;
        doff[k] = -1;
        if (i < WPOS * 8) {
            int w  = i >> 3;           // window pos 0..107
            int cq = i & 7;            // uint4 index (8 ch)
            int wr = w / WCOLS, wc = w - wr * WCOLS;
            int ny = r0 - 1 + wr, nx = c0 - 1 + wc;
            if (((unsigned)ny < (unsigned)H_) && ((unsigned)nx < (unsigned)W_))
                doff[k] = (bHW + ny * W_ + nx) * 64 + cq * 8;
        }
    }

    const size_t chunk_stride = (size_t)NPIX * 64;
    const ushort* smp_g = smp + (size_t)gi * NPOS * chunk_stride;
    ushort* swin_flat = &swin[0][0];

    f32x4 acc[4] = {};
    for (int p = 0; p < NPOS; p++) {
        // stage pointwise-W chunk into LDS: wt_[f][k0..64)
        {
            const uint4* s0 = (const uint4*)(wpwg + (size_t)rr * KC + p * 64 + seg);
            uint4 w0 = s0[0], w1 = s0[1];
            *(uint4*)&wt_[rr][seg]     = w0;
            *(uint4*)&wt_[rr][seg + 8] = w1;
        }
        // stage sample window via async global->LDS DMA (16B/lane)
        const ushort* smp_p = smp_g + (size_t)p * chunk_stride;
        #pragma unroll
        for (int k = 0; k < 4; k++) {
            int i = t + k * 256;
            if (i < WPOS * 8) {
                const ushort* src = (doff[k] >= 0) ? (smp_p + doff[k]) : zbuf;
                ushort* ldst = swin_flat + (size_t)(k * 256 + wv * 64) * 8;
                __builtin_amdgcn_global_load_lds(
                    (const __attribute__((address_space(1))) void*)src,
                    (__attribute__((address_space(3))) void*)ldst, 16, 0, 0);
            }
        }
        __syncthreads();                       // bar A (drains DMA)
        // depthwise: thread = (ch-pair cp, 8 px), float2 math, sliding window
        {
            f32x2 wd2[9];
            #pragma unroll
            for (int tap = 0; tap < 9; tap++) {
                float2 wv2 = *(const float2*)&wdwg[tap * KC + p * 64 + 2 * cp];
                wd2[tap] = {wv2.x, wv2.y};
            }
            float2 bdv = *(const float2*)&bdwg[p * 64 + 2 * cp];
            int rb0 = (pr + 0) * WCOLS + ph * 8;
            int rb1 = (pr + 1) * WCOLS + ph * 8;
            int rb2 = (pr + 2) * WCOLS + ph * 8;
            #define RD2(pos) up2(*(const unsigned*)&swin[pos][2 * cp])
            f32x2 a0 = RD2(rb0), e0 = RD2(rb0 + 1);
            f32x2 a1 = RD2(rb1), e1 = RD2(rb1 + 1);
            f32x2 a2 = RD2(rb2), e2 = RD2(rb2 + 1);
            #pragma unroll
            for (int c = 0; c < 8; c++) {
                f32x2 c0v = RD2(rb0 + c + 2);
                f32x2 c1v = RD2(rb1 + c + 2);
                f32x2 c2v = RD2(rb2 + c + 2);
                f32x2 hv = {bdv.x, bdv.y};
                hv = hv + a0 * wd2[0] + e0 * wd2[1] + c0v * wd2[2]
                        + a1 * wd2[3] + e1 * wd2[4] + c1v * wd2[5]
                        + a2 * wd2[6] + e2 * wd2[7] + c2v * wd2[8];
                int pxl = pr * 16 + ph * 8 + c;
                unsigned up = (unsigned)f2bf(hv.x) | ((unsigned)f2bf(hv.y) << 16);
                *(unsigned*)&ht[pxl][2 * cp] = up;
                a0 = e0; e0 = c0v; a1 = e1; e1 = c1v; a2 = e2; e2 = c2v;
            }
            #undef RD2
        }
        __syncthreads();                       // bar B
        // pointwise GEMM chunk: A from ht, B from wt_ (both LDS)
        #pragma unroll
        for (int ks = 0; ks < 2; ks++) {
            bf16x8 a = *(const bf16x8*)&ht[wv * 16 + hl][ks * 32 + qv * 8];
            #pragma unroll
            for (int cg = 0; cg < 4; cg++) {
                bf16x8 bfr = *(const bf16x8*)&wt_[cg * 16 + hl][ks * 32 + qv * 8];
                acc[cg] = __builtin_amdgcn_mfma_f32_16x16x32_bf16(a, bfr, acc[cg], 0, 0, 0);
            }
        }
        __syncthreads();                       // bar C (wt_/swin rewrite fence)
    }
    #pragma unroll
    for (int cg = 0; cg < 4; cg++) {
        int col = cg * 16 + hl;
        float bb = bpwg[col];
        #pragma unroll
        for (int rg = 0; rg < 4; rg++) {
            int pcol = qv * 4 + rg;
            int px = bHW + (r0 + wv) * W_ + (c0 + pcol);
            out[(size_t)px * C_ + g * CG + col] = acc[cg][rg] + bb;
        }
    }
}

// ---------------------------------------------------------------------------
// ws layout: off_all 10.6MB | yh 18.9MB | yl 18.9MB | wTh/wTl 128KB each |
//            wpwTh 288KB | wtTh/wtTl 144KB each | zbuf 128B | smp ng*42.5MB
// ---------------------------------------------------------------------------
extern "C" void kernel_launch(void* const* d_in, const int* in_sizes, int n_in,
                              void* d_out, int out_size, void* d_ws, size_t ws_size,
                              hipStream_t stream) {
    const float* x      = (const float*)d_in[0];
    const float* w_init = (const float*)d_in[1];
    const float* b_init = (const float*)d_in[2];
    const float* w_off  = (const float*)d_in[3];
    const float* b_off  = (const float*)d_in[4];
    const float* w_dw   = (const float*)d_in[5];
    const float* b_dw   = (const float*)d_in[6];
    const float* w_pw   = (const float*)d_in[7];
    const float* b_pw   = (const float*)d_in[8];
    float* out = (float*)d_out;

    float*  off_all = (float*)d_ws;
    ushort* yh      = (ushort*)(off_all + (size_t)G_ * NPIX * 18);
    ushort* yl      = yh + (size_t)NPIX * C_;
    ushort* wTh     = yl + (size_t)NPIX * C_;
    ushort* wTl     = wTh + 256 * 256;
    ushort* wpwTh   = wTl + 256 * 256;
    ushort* wtTh    = wpwTh + (size_t)G_ * KC * CG;
    ushort* wtTl    = wtTh + (size_t)G_ * 32 * KC;
    ushort* zbuf    = wtTl + (size_t)G_ * 32 * KC;
    ushort* smp     = zbuf + 64;

    size_t fixed_bytes = (size_t)((const char*)smp - (const char*)d_ws);
    size_t per_g = (size_t)NPOS * NPIX * CG * sizeof(ushort);   // 42.5 MB
    int ng = 1;
    if      (ws_size >= fixed_bytes + 4 * per_g) ng = 4;
    else if (ws_size >= fixed_bytes + 2 * per_g) ng = 2;

    k_zero<<<1, 64, 0, stream>>>(zbuf);
    k_cvt_woffT<<<(G_ * 32 * KC + 255) / 256, 256, 0, stream>>>(w_off, wtTh, wtTl);
    k_cvt_wT_split<<<(256 * 256 + 255) / 256, 256, 0, stream>>>(w_init, wTh, wTl);
    k_cvt_wpwT<<<(G_ * KC * CG + 255) / 256, 256, 0, stream>>>(w_pw, wpwTh);
    k_gemm_init_mfma<<<dim3(NPIX / 64, C_ / 64), 256, 0, stream>>>(x, wTh, wTl,
                                                                   b_init, yh, yl);
    k_offconv_mfma<<<dim3(576, G_), 256, 0, stream>>>(yh, yl, wtTh, wtTl,
                                                      b_off, off_all);

    for (int g0 = 0; g0 < G_; g0 += ng) {
        k_sample<<<dim3(NPOS * NPIX / 64, ng), 256, 0, stream>>>(yh, off_all, smp, g0);
        k_dwpw<<<dim3(576, ng), 256, 0, stream>>>(smp, zbuf, w_dw, b_dw, wpwTh,
                                                  b_pw, out, g0);
    }
}

// Round 25
// 250.258 us; speedup vs baseline: 1.0504x; 1.0504x over previous
//
#include <hip/hip_runtime.h>
#include <hip/hip_bf16.h>
#include <cstddef>

// Problem constants (B,H,W,C)=(4,96,96,256), G=4, K=3
#define B_   4
#define H_   96
#define W_   96
#define C_   256
#define G_   4
#define CG   64      // C/G
#define NPOS 9       // K*K
#define KC   576     // K*K*CG
#define HW   (H_*W_)      // 9216
#define NPIX (B_*H_*W_)   // 36864

// 2-D pixel tile (4x16, window 6x18)
#define TM 4
#define TN 16
#define WROWS 6
#define WCOLS 18
#define WPOS  108

typedef float f32x4 __attribute__((ext_vector_type(4)));
typedef float f32x2 __attribute__((ext_vector_type(2)));
typedef short bf16x8 __attribute__((ext_vector_type(8)));

static __device__ __forceinline__ ushort f2bf(float f) {
    unsigned u = __float_as_uint(f);
    unsigned r = (u + 0x7fffu + ((u >> 16) & 1u)) >> 16;   // RNE
    return (ushort)r;
}
static __device__ __forceinline__ float bf2f(ushort u) {
    return __uint_as_float(((unsigned)u) << 16);
}
static __device__ __forceinline__ f32x2 up2(unsigned u) {
    f32x2 f;
    f.x = __uint_as_float(u << 16);
    f.y = __uint_as_float(u & 0xFFFF0000u);
    return f;
}

// ---------------------------------------------------------------------------
// K0z: zero the 128B OOB source buffer (re-zeroed every launch).
// ---------------------------------------------------------------------------
__global__ void k_zero(ushort* __restrict__ z) {
    z[threadIdx.x] = 0;
}

// ---------------------------------------------------------------------------
// Kc1: w_off [g][3][3][64][18] -> wtT split bf16 [g][oc pad 32][576]
// ---------------------------------------------------------------------------
__global__ void k_cvt_woffT(const float* __restrict__ w_off,
                            ushort* __restrict__ wtTh,
                            ushort* __restrict__ wtTl) {
    int idx = blockIdx.x * 256 + threadIdx.x;
    if (idx >= G_ * 32 * KC) return;
    int k  = idx % KC;
    int oc = (idx / KC) & 31;
    int g  = idx / (32 * KC);
    int p = k >> 6, c = k & 63;
    float v = 0.f;
    if (oc < 18) v = w_off[((size_t)(g * NPOS + p) * CG + c) * 18 + oc];
    ushort h = f2bf(v);
    wtTh[idx] = h;
    wtTl[idx] = f2bf(v - bf2f(h));
}

// ---------------------------------------------------------------------------
// Kc2: w_init [k=256][co=256] -> wT split bf16 [co][k]
// ---------------------------------------------------------------------------
__global__ void k_cvt_wT_split(const float* __restrict__ w_init,
                               ushort* __restrict__ wTh,
                               ushort* __restrict__ wTl) {
    int idx = blockIdx.x * 256 + threadIdx.x;
    if (idx >= 256 * 256) return;
    int co = idx & 255, k = idx >> 8;
    float v = w_init[(size_t)k * 256 + co];
    ushort h = f2bf(v);
    wTh[(size_t)co * 256 + k] = h;
    wTl[(size_t)co * 256 + k] = f2bf(v - bf2f(h));
}

// ---------------------------------------------------------------------------
// Kc3: w_pw [g][k=576][f=64] -> wpwT bf16 (hi only) [g][f][k=576]
// ---------------------------------------------------------------------------
__global__ void k_cvt_wpwT(const float* __restrict__ w_pw,
                           ushort* __restrict__ wpwTh) {
    int idx = blockIdx.x * 256 + threadIdx.x;
    if (idx >= G_ * KC * CG) return;
    int f = idx & 63;
    int k = (idx >> 6) % KC;
    int g = idx / (KC * CG);
    wpwTh[((size_t)g * CG + f) * KC + k] = f2bf(w_pw[((size_t)g * KC + k) * CG + f]);
}

// ---------------------------------------------------------------------------
// K1: init 1x1 conv via split-bf16 MFMA (~f32 exact). y -> (yh, yl).
// ---------------------------------------------------------------------------
__global__ void __launch_bounds__(256) k_gemm_init_mfma(
        const float* __restrict__ x,
        const ushort* __restrict__ wTh, const ushort* __restrict__ wTl,
        const float* __restrict__ bias,
        ushort* __restrict__ yh, ushort* __restrict__ yl) {
    __shared__ __align__(16) ushort ath[64][72], atl[64][72];
    __shared__ __align__(16) ushort bth[64][72], btl[64][72];
    int t = threadIdx.x;
    int px0 = blockIdx.x * 64, n0 = blockIdx.y * 64;
    int r = t >> 2, seg = (t & 3) * 16;
    int lane = t & 63, wv = t >> 6;
    int hl = lane & 15, qv = lane >> 4;
    f32x4 acc[4] = {};
    for (int kk = 0; kk < C_; kk += 64) {
        {
            const float4* xs = (const float4*)(x + (size_t)(px0 + r) * C_ + kk + seg);
            ushort hbuf[16], lbuf[16];
            #pragma unroll
            for (int j = 0; j < 4; j++) {
                float4 v = xs[j];
                float vv[4] = {v.x, v.y, v.z, v.w};
                #pragma unroll
                for (int e2 = 0; e2 < 4; e2++) {
                    ushort h = f2bf(vv[e2]);
                    hbuf[j * 4 + e2] = h;
                    lbuf[j * 4 + e2] = f2bf(vv[e2] - bf2f(h));
                }
            }
            *(uint4*)&ath[r][seg]     = *(uint4*)&hbuf[0];
            *(uint4*)&ath[r][seg + 8] = *(uint4*)&hbuf[8];
            *(uint4*)&atl[r][seg]     = *(uint4*)&lbuf[0];
            *(uint4*)&atl[r][seg + 8] = *(uint4*)&lbuf[8];
        }
        {
            size_t woff = (size_t)(n0 + r) * C_ + kk + seg;
            const uint4* qh = (const uint4*)(wTh + woff);
            const uint4* ql = (const uint4*)(wTl + woff);
            uint4 c0 = qh[0], c1 = qh[1], d0 = ql[0], d1 = ql[1];
            *(uint4*)&bth[r][seg] = c0; *(uint4*)&bth[r][seg + 8] = c1;
            *(uint4*)&btl[r][seg] = d0; *(uint4*)&btl[r][seg + 8] = d1;
        }
        __syncthreads();
        #pragma unroll
        for (int ks = 0; ks < 2; ks++) {
            bf16x8 ah_ = *(const bf16x8*)&ath[wv * 16 + hl][ks * 32 + qv * 8];
            bf16x8 al_ = *(const bf16x8*)&atl[wv * 16 + hl][ks * 32 + qv * 8];
            #pragma unroll
            for (int cg = 0; cg < 4; cg++) {
                bf16x8 bh_ = *(const bf16x8*)&bth[cg * 16 + hl][ks * 32 + qv * 8];
                bf16x8 bl_ = *(const bf16x8*)&btl[cg * 16 + hl][ks * 32 + qv * 8];
                acc[cg] = __builtin_amdgcn_mfma_f32_16x16x32_bf16(ah_, bh_, acc[cg], 0, 0, 0);
                acc[cg] = __builtin_amdgcn_mfma_f32_16x16x32_bf16(ah_, bl_, acc[cg], 0, 0, 0);
                acc[cg] = __builtin_amdgcn_mfma_f32_16x16x32_bf16(al_, bh_, acc[cg], 0, 0, 0);
            }
        }
        __syncthreads();
    }
    #pragma unroll
    for (int cg = 0; cg < 4; cg++) {
        int col = n0 + cg * 16 + hl;
        float bb = bias[col];
        #pragma unroll
        for (int rg = 0; rg < 4; rg++) {
            int row = px0 + wv * 16 + qv * 4 + rg;
            float v = acc[cg][rg] + bb;
            ushort h = f2bf(v);
            yh[(size_t)row * C_ + col] = h;
            yl[(size_t)row * C_ + col] = f2bf(v - bf2f(h));
        }
    }
}

// ---------------------------------------------------------------------------
// K2: offsets 3x3 conv (64 -> 18) via 4-term split-bf16 MFMA (f32-equiv).
// R21 version EXACTLY (85 us measured).
// ---------------------------------------------------------------------------
__global__ void __launch_bounds__(256) k_offconv_mfma(
        const ushort* __restrict__ yh, const ushort* __restrict__ yl,
        const ushort* __restrict__ wtTh, const ushort* __restrict__ wtTl,
        const float* __restrict__ b_off, float* __restrict__ off_all) {
    __shared__ __align__(16) ushort swh[WPOS][72], swl[WPOS][72];  // 31.1 KB
    int g = blockIdx.y;
    int tile = blockIdx.x;
    int b = tile / 144; int trem = tile - b * 144;
    int r0 = (trem / 6) * TM;
    int c0 = (trem - (trem / 6) * 6) * TN;
    int t = threadIdx.x;
    int lane = t & 63, wv = t >> 6;
    int hl = lane & 15, qv = lane >> 4;
    const int bHW = b * HW;
    for (int i = t; i < WPOS * 32; i += 256) {
        int w = i >> 5, cq = i & 31;
        int wr = w / WCOLS, wc = w - wr * WCOLS;
        int ny = r0 - 1 + wr, nx = c0 - 1 + wc;
        unsigned vh = 0u, vl = 0u;
        if (((unsigned)ny < (unsigned)H_) && ((unsigned)nx < (unsigned)W_)) {
            size_t base = ((size_t)(bHW + ny * W_ + nx) * C_ + g * CG) >> 1;
            vh = ((const unsigned*)yh)[base + cq];
            vl = ((const unsigned*)yl)[base + cq];
        }
        *(unsigned*)&swh[w][cq * 2] = vh;
        *(unsigned*)&swl[w][cq * 2] = vl;
    }
    __syncthreads();
    f32x4 acc[2] = {};
    const ushort* Wh = wtTh + (size_t)g * 32 * KC;
    const ushort* Wl = wtTl + (size_t)g * 32 * KC;
    const size_t wbase0 = (size_t)hl * KC + qv * 8;
    bf16x8 nbh[2][2], nbl[2][2];
    #pragma unroll
    for (int ks = 0; ks < 2; ks++)
        #pragma unroll
        for (int cg = 0; cg < 2; cg++) {
            size_t wo = wbase0 + (size_t)cg * 16 * KC + ks * 32;
            nbh[ks][cg] = *(const bf16x8*)&Wh[wo];
            nbl[ks][cg] = *(const bf16x8*)&Wl[wo];
        }
    for (int p = 0; p < NPOS; p++) {
        bf16x8 cbh[2][2], cbl[2][2];
        #pragma unroll
        for (int ks = 0; ks < 2; ks++)
            #pragma unroll
            for (int cg = 0; cg < 2; cg++) {
                cbh[ks][cg] = nbh[ks][cg];
                cbl[ks][cg] = nbl[ks][cg];
            }
        if (p + 1 < NPOS) {
            #pragma unroll
            for (int ks = 0; ks < 2; ks++)
                #pragma unroll
                for (int cg = 0; cg < 2; cg++) {
                    size_t wo = wbase0 + (size_t)cg * 16 * KC + (p + 1) * 64 + ks * 32;
                    nbh[ks][cg] = *(const bf16x8*)&Wh[wo];
                    nbl[ks][cg] = *(const bf16x8*)&Wl[wo];
                }
        }
        int di = p / 3, dj = p - di * 3;
        int wbase = (wv + di) * WCOLS + dj + hl;
        #pragma unroll
        for (int ks = 0; ks < 2; ks++) {
            bf16x8 ah = *(const bf16x8*)&swh[wbase][ks * 32 + qv * 8];
            bf16x8 al = *(const bf16x8*)&swl[wbase][ks * 32 + qv * 8];
            #pragma unroll
            for (int cg = 0; cg < 2; cg++) {
                acc[cg] = __builtin_amdgcn_mfma_f32_16x16x32_bf16(ah, cbh[ks][cg], acc[cg], 0, 0, 0);
                acc[cg] = __builtin_amdgcn_mfma_f32_16x16x32_bf16(ah, cbl[ks][cg], acc[cg], 0, 0, 0);
                acc[cg] = __builtin_amdgcn_mfma_f32_16x16x32_bf16(al, cbh[ks][cg], acc[cg], 0, 0, 0);
                acc[cg] = __builtin_amdgcn_mfma_f32_16x16x32_bf16(al, cbl[ks][cg], acc[cg], 0, 0, 0);
            }
        }
    }
    #pragma unroll
    for (int cg = 0; cg < 2; cg++) {
        int oc = cg * 16 + hl;
        if (oc < 18) {
            float bo = b_off[g * 18 + oc];
            #pragma unroll
            for (int rg = 0; rg < 4; rg++) {
                int pc = qv * 4 + rg;
                int px = bHW + (r0 + wv) * W_ + (c0 + pc);
                off_all[((size_t)g * NPIX + px) * 18 + oc] = acc[cg][rg] + bo;
            }
        }
    }
}

// ---------------------------------------------------------------------------
// K3: sampling (per pass). 8 ch per lane (uint4), 8 samples per
// wave-iteration (R19-proven; R24's swizzle reverted -- neutral/negative).
// ---------------------------------------------------------------------------
__global__ void __launch_bounds__(256) k_sample(
        const ushort* __restrict__ yh, const float* __restrict__ off_all,
        ushort* __restrict__ smp, int g0) {
    int gi = blockIdx.y;
    int g = g0 + gi;
    int t = threadIdx.x;
    int lane = t & 63, wv = t >> 6;
    int so = lane >> 3;          // sample-octet select 0..7
    int cq = lane & 7;           // uint4 channel index (8 ch)
    int base_s = (blockIdx.x * 4 + wv) * 16;
    const float* offg = off_all + (size_t)g * NPIX * 18;
    const uint4* ybu = (const uint4*)yh;        // pix stride = 32 uint4
    uint4* smp4 = (uint4*)smp + (size_t)gi * NPOS * NPIX * 8;
    #pragma unroll
    for (int q = 0; q < 2; q++) {
        int s = base_s + q * 8 + so;
        int p = s / NPIX;
        int px = s - p * NPIX;
        int di = p / 3, dj = p - di * 3;
        int b = px / HW; int r2 = px - b * HW;
        int yy = r2 / W_; int xx = r2 - yy * W_;
        float2 o2 = *(const float2*)&offg[(size_t)px * 18 + 2 * p];
        float lx = (float)(xx + dj - 1) + o2.x;
        float ly = (float)(yy + di - 1) + o2.y;
        lx = fminf(fmaxf(lx, 0.f), (float)(W_ - 1));
        ly = fminf(fmaxf(ly, 0.f), (float)(H_ - 1));
        float x0f = floorf(lx), y0f = floorf(ly);
        float x1f = fminf(x0f + 1.f, (float)(W_ - 1));
        float y1f = fminf(y0f + 1.f, (float)(H_ - 1));
        float wa = (x1f - lx) * (y1f - ly);
        float wb = (x1f - lx) * (ly - y0f);
        float wc = (lx - x0f) * (y1f - ly);
        float wd = (lx - x0f) * (ly - y0f);
        int ix0 = (int)x0f, iy0 = (int)y0f, ix1 = (int)x1f, iy1 = (int)y1f;
        int pb = (b * HW) * 32 + g * 8 + cq;
        uint4 A  = ybu[pb + (iy0 * W_ + ix0) * 32];
        uint4 Bv = ybu[pb + (iy1 * W_ + ix0) * 32];
        uint4 Cv = ybu[pb + (iy0 * W_ + ix1) * 32];
        uint4 Dv = ybu[pb + (iy1 * W_ + ix1) * 32];
        f32x2 v0 = wa * up2(A.x) + wb * up2(Bv.x) + wc * up2(Cv.x) + wd * up2(Dv.x);
        f32x2 v1 = wa * up2(A.y) + wb * up2(Bv.y) + wc * up2(Cv.y) + wd * up2(Dv.y);
        f32x2 v2 = wa * up2(A.z) + wb * up2(Bv.z) + wc * up2(Cv.z) + wd * up2(Dv.z);
        f32x2 v3 = wa * up2(A.w) + wb * up2(Bv.w) + wc * up2(Cv.w) + wd * up2(Dv.w);
        uint4 o;
        o.x = (unsigned)f2bf(v0.x) | ((unsigned)f2bf(v0.y) << 16);
        o.y = (unsigned)f2bf(v1.x) | ((unsigned)f2bf(v1.y) << 16);
        o.z = (unsigned)f2bf(v2.x) | ((unsigned)f2bf(v2.y) << 16);
        o.w = (unsigned)f2bf(v3.x) | ((unsigned)f2bf(v3.y) << 16);
        smp4[(size_t)s * 8 + cq] = o;
    }
}

// ---------------------------------------------------------------------------
// K4: window-stage + depthwise-3x3 + bf16-MFMA pointwise (per pass).
// R21 structure with bar B REMOVED: ht rows are wave-private (pr == t>>6 ==
// wv: wave wv's dw phase writes exactly rows [wv*16, wv*16+16) and its MFMA
// reads exactly those rows), so the dw->MFMA barrier is unnecessary --
// in-wave lgkmcnt ordering (compiler-inserted) suffices. 2 barriers/chunk.
// Everything else identical to R21 (best measured).
// ---------------------------------------------------------------------------
__global__ void __launch_bounds__(256, 4) k_dwpw(
        const ushort* __restrict__ smp, const ushort* __restrict__ zbuf,
        const float* __restrict__ w_dw, const float* __restrict__ b_dw,
        const ushort* __restrict__ wpwTh, const float* __restrict__ b_pw,
        float* __restrict__ out, int g0) {
    __shared__ __align__(16) ushort swin[WPOS][64];   // 13.5 KB [pos][ch]
    __shared__ __align__(16) ushort ht [64][72];      //  9.0 KB
    __shared__ __align__(16) ushort wt_[64][72];      //  9.0 KB
    int gi = blockIdx.y;
    int g = g0 + gi;
    int bx = blockIdx.x;
    int tile = (bx & 7) * 72 + (bx >> 3);   // bijective (576 = 8*72)
    int b = tile / 144; int trem = tile - b * 144;
    int r0 = (trem / 6) * TM;
    int c0 = (trem - (trem / 6) * 6) * TN;
    int t = threadIdx.x;
    int lane = t & 63, wv = t >> 6;
    int hl = lane & 15, qv = lane >> 4;
    int rr = t >> 2, seg = (t & 3) * 16;
    const float* wdwg = w_dw + (size_t)g * NPOS * KC;
    const float* bdwg = b_dw + (size_t)g * KC;
    const ushort* wpwg = wpwTh + (size_t)g * CG * KC;
    const float* bpwg = b_pw + (size_t)g * CG;
    const int bHW = b * HW;
    int cp  = t & 31;          // channel pair (2cp, 2cp+1)
    int pxg = t >> 5;          // 0..7
    int pr  = pxg >> 1;        // tile row 0..3  (== wv: ht is wave-private)
    int ph  = pxg & 1;         // col half (8 cols each)

    // staging descriptors: 108 pos x 8 uint4 = 864 items, up to 4 per thread
    int doff[4];
    #pragma unroll
    for (int k = 0; k < 4; k++) {
        int i = t + k * 256;
        doff[k] = -1;
        if (i < WPOS * 8) {
            int w  = i >> 3;           // window pos 0..107
            int cq = i & 7;            // uint4 index (8 ch)
            int wr = w / WCOLS, wc = w - wr * WCOLS;
            int ny = r0 - 1 + wr, nx = c0 - 1 + wc;
            if (((unsigned)ny < (unsigned)H_) && ((unsigned)nx < (unsigned)W_))
                doff[k] = (bHW + ny * W_ + nx) * 64 + cq * 8;
        }
    }

    const size_t chunk_stride = (size_t)NPIX * 64;
    const ushort* smp_g = smp + (size_t)gi * NPOS * chunk_stride;
    ushort* swin_flat = &swin[0][0];

    f32x4 acc[4] = {};
    for (int p = 0; p < NPOS; p++) {
        // stage pointwise-W chunk into LDS: wt_[f][k0..64)
        {
            const uint4* s0 = (const uint4*)(wpwg + (size_t)rr * KC + p * 64 + seg);
            uint4 w0 = s0[0], w1 = s0[1];
            *(uint4*)&wt_[rr][seg]     = w0;
            *(uint4*)&wt_[rr][seg + 8] = w1;
        }
        // stage sample window via async global->LDS DMA (16B/lane)
        const ushort* smp_p = smp_g + (size_t)p * chunk_stride;
        #pragma unroll
        for (int k = 0; k < 4; k++) {
            int i = t + k * 256;
            if (i < WPOS * 8) {
                const ushort* src = (doff[k] >= 0) ? (smp_p + doff[k]) : zbuf;
                ushort* ldst = swin_flat + (size_t)(k * 256 + wv * 64) * 8;
                __builtin_amdgcn_global_load_lds(
                    (const __attribute__((address_space(1))) void*)src,
                    (__attribute__((address_space(3))) void*)ldst, 16, 0, 0);
            }
        }
        __syncthreads();                       // bar A (drains DMA + wt_ writes)
        // depthwise: thread = (ch-pair cp, 8 px of row pr == wv), float2 math
        {
            f32x2 wd2[9];
            #pragma unroll
            for (int tap = 0; tap < 9; tap++) {
                float2 wv2 = *(const float2*)&wdwg[tap * KC + p * 64 + 2 * cp];
                wd2[tap] = {wv2.x, wv2.y};
            }
            float2 bdv = *(const float2*)&bdwg[p * 64 + 2 * cp];
            int rb0 = (pr + 0) * WCOLS + ph * 8;
            int rb1 = (pr + 1) * WCOLS + ph * 8;
            int rb2 = (pr + 2) * WCOLS + ph * 8;
            #define RD2(pos) up2(*(const unsigned*)&swin[pos][2 * cp])
            f32x2 a0 = RD2(rb0), e0 = RD2(rb0 + 1);
            f32x2 a1 = RD2(rb1), e1 = RD2(rb1 + 1);
            f32x2 a2 = RD2(rb2), e2 = RD2(rb2 + 1);
            #pragma unroll
            for (int c = 0; c < 8; c++) {
                f32x2 c0v = RD2(rb0 + c + 2);
                f32x2 c1v = RD2(rb1 + c + 2);
                f32x2 c2v = RD2(rb2 + c + 2);
                f32x2 hv = {bdv.x, bdv.y};
                hv = hv + a0 * wd2[0] + e0 * wd2[1] + c0v * wd2[2]
                        + a1 * wd2[3] + e1 * wd2[4] + c1v * wd2[5]
                        + a2 * wd2[6] + e2 * wd2[7] + c2v * wd2[8];
                int pxl = pr * 16 + ph * 8 + c;
                unsigned up = (unsigned)f2bf(hv.x) | ((unsigned)f2bf(hv.y) << 16);
                *(unsigned*)&ht[pxl][2 * cp] = up;
                a0 = e0; e0 = c0v; a1 = e1; e1 = c1v; a2 = e2; e2 = c2v;
            }
            #undef RD2
        }
        // NO barrier here: ht rows [wv*16, wv*16+16) are written and read by
        // the same wave; lgkmcnt ordering is compiler-enforced.
        // pointwise GEMM chunk: A from ht, B from wt_ (both LDS)
        #pragma unroll
        for (int ks = 0; ks < 2; ks++) {
            bf16x8 a = *(const bf16x8*)&ht[wv * 16 + hl][ks * 32 + qv * 8];
            #pragma unroll
            for (int cg = 0; cg < 4; cg++) {
                bf16x8 bfr = *(const bf16x8*)&wt_[cg * 16 + hl][ks * 32 + qv * 8];
                acc[cg] = __builtin_amdgcn_mfma_f32_16x16x32_bf16(a, bfr, acc[cg], 0, 0, 0);
            }
        }
        __syncthreads();                       // bar C (swin/wt_ rewrite fence)
    }
    #pragma unroll
    for (int cg = 0; cg < 4; cg++) {
        int col = cg * 16 + hl;
        float bb = bpwg[col];
        #pragma unroll
        for (int rg = 0; rg < 4; rg++) {
            int pcol = qv * 4 + rg;
            int px = bHW + (r0 + wv) * W_ + (c0 + pcol);
            out[(size_t)px * C_ + g * CG + col] = acc[cg][rg] + bb;
        }
    }
}

// ---------------------------------------------------------------------------
// ws layout: off_all 10.6MB | yh 18.9MB | yl 18.9MB | wTh/wTl 128KB each |
//            wpwTh 288KB | wtTh/wtTl 144KB each | zbuf 128B | smp ng*42.5MB
// ---------------------------------------------------------------------------
extern "C" void kernel_launch(void* const* d_in, const int* in_sizes, int n_in,
                              void* d_out, int out_size, void* d_ws, size_t ws_size,
                              hipStream_t stream) {
    const float* x      = (const float*)d_in[0];
    const float* w_init = (const float*)d_in[1];
    const float* b_init = (const float*)d_in[2];
    const float* w_off  = (const float*)d_in[3];
    const float* b_off  = (const float*)d_in[4];
    const float* w_dw   = (const float*)d_in[5];
    const float* b_dw   = (const float*)d_in[6];
    const float* w_pw   = (const float*)d_in[7];
    const float* b_pw   = (const float*)d_in[8];
    float* out = (float*)d_out;

    float*  off_all = (float*)d_ws;
    ushort* yh      = (ushort*)(off_all + (size_t)G_ * NPIX * 18);
    ushort* yl      = yh + (size_t)NPIX * C_;
    ushort* wTh     = yl + (size_t)NPIX * C_;
    ushort* wTl     = wTh + 256 * 256;
    ushort* wpwTh   = wTl + 256 * 256;
    ushort* wtTh    = wpwTh + (size_t)G_ * KC * CG;
    ushort* wtTl    = wtTh + (size_t)G_ * 32 * KC;
    ushort* zbuf    = wtTl + (size_t)G_ * 32 * KC;
    ushort* smp     = zbuf + 64;

    size_t fixed_bytes = (size_t)((const char*)smp - (const char*)d_ws);
    size_t per_g = (size_t)NPOS * NPIX * CG * sizeof(ushort);   // 42.5 MB
    int ng = 1;
    if      (ws_size >= fixed_bytes + 4 * per_g) ng = 4;
    else if (ws_size >= fixed_bytes + 2 * per_g) ng = 2;

    k_zero<<<1, 64, 0, stream>>>(zbuf);
    k_cvt_woffT<<<(G_ * 32 * KC + 255) / 256, 256, 0, stream>>>(w_off, wtTh, wtTl);
    k_cvt_wT_split<<<(256 * 256 + 255) / 256, 256, 0, stream>>>(w_init, wTh, wTl);
    k_cvt_wpwT<<<(G_ * KC * CG + 255) / 256, 256, 0, stream>>>(w_pw, wpwTh);
    k_gemm_init_mfma<<<dim3(NPIX / 64, C_ / 64), 256, 0, stream>>>(x, wTh, wTl,
                                                                   b_init, yh, yl);
    k_offconv_mfma<<<dim3(576, G_), 256, 0, stream>>>(yh, yl, wtTh, wtTl,
                                                      b_off, off_all);

    for (int g0 = 0; g0 < G_; g0 += ng) {
        k_sample<<<dim3(NPOS * NPIX / 64, ng), 256, 0, stream>>>(yh, off_all, smp, g0);
        k_dwpw<<<dim3(576, ng), 256, 0, stream>>>(smp, zbuf, w_dw, b_dw, wpwTh,
                                                  b_pw, out, g0);
    }
}